// Round 4
// baseline (199.538 us; speedup 1.0000x reference)
//
#include <hip/hip_runtime.h>

// PSU LIF: V_t = b*V_{t-1} + x_t ; R_t = b*R_{t-1} + sigmoid(V_t)
// out0 = (V - R - 1 > 0), out1 = V.  x:[16,1024,1024] f32, beta:[1024] f32.
//
// Round-4: same chunked in-block scan as round 3 (block = 32 seq x 32 chunks,
// L=32, carries via LDS). Changes:
//   - __launch_bounds__(1024, 8): cap VGPR at 64 -> guarantees 2 blocks/CU
//     (32 waves/CU, max occupancy). Round-2 evidence: compiler hits 64 here.
//   - sigmoid via __builtin_amdgcn_rcpf: avoids the ~10-instr exact-division
//     sequence (no fast-math flags in harness). 1-ulp error, thr = 2.37.
//   - nontemporal loads/stores: 201MB pure streaming, zero reuse.
// Traffic optimum: read x 67MB, write V+spike 134MB -> ~30us floor.

#define BB 16
#define TT 1024
#define HH 1024
#define L 32            // timesteps per thread
#define C 32            // chunks per sequence = TT/L
#define SEQ 32          // sequences per block

__global__ __launch_bounds__(1024, 8) void lif_scan(const float* __restrict__ x,
                                                    const float* __restrict__ beta,
                                                    float* __restrict__ out_spike,
                                                    float* __restrict__ out_v) {
    __shared__ float lds_v[C][SEQ];         // 4 KB: chunk-final local V sums
    __shared__ float lds_r[C][SEQ];         // 4 KB: chunk-final local R sums

    const int tid = threadIdx.x;
    const int c = tid >> 5;                 // chunk index 0..31
    const int s = tid & 31;                 // sequence-in-block 0..31
    const int blk = blockIdx.x;             // 512 blocks
    const int b = blk >> 5;                 // batch (32 blocks per batch)
    const int h = ((blk & 31) << 5) + s;    // hidden index

    const float bf = fminf(fmaxf(beta[h], 0.0f), 1.0f);
    float pwL = bf;                         // b^L via 5 squarings (L=32)
#pragma unroll
    for (int k = 0; k < 5; ++k) pwL *= pwL;

    const size_t base = (size_t)b * TT * HH + (size_t)(c * L) * HH + (size_t)h;
    const float* __restrict__ xp = x + base;
    float* __restrict__ vp = out_v + base;
    float* __restrict__ sp = out_spike + base;

    // ---- load chunk (32 independent nontemporal loads in flight) ----
    float arr[L];
#pragma unroll
    for (int i = 0; i < L; ++i) arr[i] = __builtin_nontemporal_load(xp + (size_t)i * HH);

    // ---- phase A: local V scan (zero init) ----
    float V = 0.0f;
#pragma unroll
    for (int i = 0; i < L; ++i) {
        V = fmaf(bf, V, arr[i]);
        arr[i] = V;
    }
    lds_v[c][s] = V;
    __syncthreads();

    // ---- V carry: Vstart(c) = sum_{j<c} (b^L)^(c-1-j) * vsum_j ----
    float Vstart = 0.0f;
    for (int j = 0; j < c; ++j) Vstart = fmaf(pwL, Vstart, lds_v[j][s]);

    // ---- phase B: exact V, write V, sigmoid, local R scan ----
    float vcarry = Vstart;
    float R = 0.0f;
#pragma unroll
    for (int i = 0; i < L; ++i) {
        vcarry *= bf;                       // b^(i+1) * Vstart
        const float vfull = arr[i] + vcarry;
        __builtin_nontemporal_store(vfull, vp + (size_t)i * HH);
        const float sg = __builtin_amdgcn_rcpf(1.0f + __expf(-vfull));
        R = fmaf(bf, R, sg);
        arr[i] = vfull - R;                 // e_i = V_i - localR_i
    }
    lds_r[c][s] = R;
    __syncthreads();

    // ---- R carry ----
    float Rstart = 0.0f;
    for (int j = 0; j < c; ++j) Rstart = fmaf(pwL, Rstart, lds_r[j][s]);

    // ---- phase C: spike = (e_i - b^(i+1)*Rstart > 1) ----
    float rcarry = Rstart;
#pragma unroll
    for (int i = 0; i < L; ++i) {
        rcarry *= bf;
        const float spike = (arr[i] - rcarry > 1.0f) ? 1.0f : 0.0f;
        __builtin_nontemporal_store(spike, sp + (size_t)i * HH);
    }
}

extern "C" void kernel_launch(void* const* d_in, const int* in_sizes, int n_in,
                              void* d_out, int out_size, void* d_ws, size_t ws_size,
                              hipStream_t stream) {
    const float* x = (const float*)d_in[0];
    const float* beta = (const float*)d_in[1];
    float* out = (float*)d_out;
    float* out_spike = out;                              // [16,1024,1024]
    float* out_v = out + (size_t)BB * TT * HH;           // [16,1024,1024]

    const int grid = (BB * HH) / SEQ;                    // 512 blocks
    lif_scan<<<grid, 1024, 0, stream>>>(x, beta, out_spike, out_v);
}